// Round 2
// baseline (1774.607 us; speedup 1.0000x reference)
//
#include <hip/hip_runtime.h>
#include <cstdint>
#include <cstddef>

#define BATCH_N 32768
#define IND 768
#define HID 2048

typedef __attribute__((ext_vector_type(4))) float float4v;
typedef __attribute__((ext_vector_type(4))) _Float16 half4v;
typedef __attribute__((ext_vector_type(8))) _Float16 half8v;

// ---------------- prep: W_enc -> fp16, scaled by 1024 ------------------------
__global__ __launch_bounds__(256) void prep_wenc(const float* __restrict__ W,
                                                 _Float16* __restrict__ Whi)
{
    const int t = blockIdx.x * 256 + threadIdx.x;   // 0 .. 2048*768/4-1
    float4v f = ((const float4v*)W)[t];
    half4v hv = {(_Float16)(f.x * 1024.0f), (_Float16)(f.y * 1024.0f),
                 (_Float16)(f.z * 1024.0f), (_Float16)(f.w * 1024.0f)};
    ((half4v*)Whi)[t] = hv;
}

// ---------------- prep: W_dec [768][2048] -> W_decT [2048][768] fp32 ---------
__global__ __launch_bounds__(256) void prep_wdec(const float* __restrict__ Wd,
                                                 float* __restrict__ WdT)
{
    const int t = blockIdx.x * 256 + threadIdx.x;   // over 2048*768 outputs
    const int h = t / IND;
    const int d = t - h * IND;
    WdT[t] = Wd[(size_t)d * HID + h];
}

// ---------------- encoder GEMM (approx): h~ = x @ W_enc^T + b_enc ------------
// single fp16 MFMA, W pre-scaled by 1024, epilogue rescales by 2^-10.
// 128x128 tile, BK=32, 4 waves. Error ~1.4e-4 RMS — plenty for outputs and
// for top-40 candidate screening; exact selection happens in topk_refine.
__global__ __launch_bounds__(256) void gemm_enc(
    const float* __restrict__ x, const _Float16* __restrict__ Whi,
    const float* __restrict__ benc, float* __restrict__ hpre)
{
    __shared__ __align__(16) _Float16 sAh[128 * 32];
    __shared__ __align__(16) _Float16 sBh[128 * 32];

    const int tid  = threadIdx.x;
    const int lane = tid & 63;
    const int wave = tid >> 6;
    const int mt = blockIdx.x >> 4;     // 256 m-tiles
    const int nt = blockIdx.x & 15;     // 16 n-tiles
    const int M0 = mt << 7, N0 = nt << 7;

    // staging map: 2 threads per tile-row, 16 elements each
    const int srow  = tid >> 1;
    const int shalf = (tid & 1) << 4;   // 0 or 16 (elements)
    const float*    xg  = x   + (size_t)(M0 + srow) * IND + shalf;
    const _Float16* bhg = Whi + (size_t)(N0 + srow) * IND + shalf;
    _Float16* sah = sAh + srow * 32 + shalf;
    _Float16* sbh = sBh + srow * 32 + shalf;

    const int wm  = (wave & 1) << 6;
    const int wn  = (wave >> 1) << 6;
    const int fr  = lane & 15;
    const int fko = (lane >> 4) << 3;

    float4v acc[4][4] = {};

#pragma unroll 1
    for (int kt = 0; kt < 24; ++kt) {
        const int k0 = kt << 5;
        float4v f0 = *(const float4v*)(xg + k0);
        float4v f1 = *(const float4v*)(xg + k0 + 4);
        float4v f2 = *(const float4v*)(xg + k0 + 8);
        float4v f3 = *(const float4v*)(xg + k0 + 12);
        half8v wh0 = *(const half8v*)(bhg + k0);
        half8v wh1 = *(const half8v*)(bhg + k0 + 8);

        __syncthreads();   // previous iteration's LDS reads done

        half8v ha0 = {(_Float16)f0.x, (_Float16)f0.y, (_Float16)f0.z, (_Float16)f0.w,
                      (_Float16)f1.x, (_Float16)f1.y, (_Float16)f1.z, (_Float16)f1.w};
        half8v ha1 = {(_Float16)f2.x, (_Float16)f2.y, (_Float16)f2.z, (_Float16)f2.w,
                      (_Float16)f3.x, (_Float16)f3.y, (_Float16)f3.z, (_Float16)f3.w};
        *(half8v*)(sah)     = ha0;
        *(half8v*)(sah + 8) = ha1;
        *(half8v*)(sbh)     = wh0;
        *(half8v*)(sbh + 8) = wh1;

        __syncthreads();

        half8v Ah[4], Bh[4];
#pragma unroll
        for (int i = 0; i < 4; ++i) {
            Ah[i] = *(const half8v*)&sAh[(wm + i*16 + fr)*32 + fko];
            Bh[i] = *(const half8v*)&sBh[(wn + i*16 + fr)*32 + fko];
        }
#pragma unroll
        for (int i = 0; i < 4; ++i)
#pragma unroll
            for (int j = 0; j < 4; ++j)
                acc[i][j] = __builtin_amdgcn_mfma_f32_16x16x32_f16(Ah[i], Bh[j], acc[i][j], 0, 0, 0);
    }

    // epilogue: rescale by 2^-10, add bias, store.
    // C/D mapping (m89/m91-verified): col = lane&15, row = (lane>>4)*4 + reg
    const float inv = 1.0f / 1024.0f;
#pragma unroll
    for (int j = 0; j < 4; ++j) {
        const int col = N0 + wn + j*16 + fr;
        const float bias = benc[col];
#pragma unroll
        for (int i = 0; i < 4; ++i) {
            const int row0 = M0 + wm + i*16 + ((lane >> 4) << 2);
            float* p = hpre + (size_t)row0 * HID + col;
            p[0]       = acc[i][j][0] * inv + bias;
            p[HID]     = acc[i][j][1] * inv + bias;
            p[2 * HID] = acc[i][j][2] * inv + bias;
            p[3 * HID] = acc[i][j][3] * inv + bias;
        }
    }
}

// ---------------- top-k with exact fp64 refinement ---------------------------
// One wave per row. Approx top-40 from h~ (screen), exact fp64 dot for the 40
// candidates, drop the 8 smallest exact (ties: larger index dropped first, so
// smaller index wins — matches lax.top_k), scatter h_sparse, emit idx/val.
__global__ __launch_bounds__(256) void topk_refine(
    const float* __restrict__ hpre, const float* __restrict__ x,
    const float* __restrict__ Wenc, const float* __restrict__ benc,
    float* __restrict__ hsp, int* __restrict__ oidx, float* __restrict__ oval)
{
    const int lane = threadIdx.x & 63;
    const int wave = threadIdx.x >> 6;
    const int row  = blockIdx.x * 4 + wave;
    const float* hp = hpre + (size_t)row * HID;

    float v[32];
#pragma unroll
    for (int i = 0; i < 32; ++i) v[i] = hp[i * 64 + lane];

    unsigned sel = 0;
    float lmax = v[0]; int larg = 0;
#pragma unroll
    for (int i = 1; i < 32; ++i) if (v[i] > lmax) { lmax = v[i]; larg = i; }

    float selval = 0.0f; int selidx = -1;
    for (int it = 0; it < 40; ++it) {
        float bv = lmax;
        int bg = (larg << 6) | lane;          // global column index
#pragma unroll
        for (int off = 32; off > 0; off >>= 1) {
            float ov = __shfl_xor(bv, off);
            int   og = __shfl_xor(bg, off);
            if (ov > bv || (ov == bv && og < bg)) { bv = ov; bg = og; }
        }
        if (lane == it) { selval = bv; selidx = bg; }
        if ((bg & 63) == lane) {              // I own the winner: remove & rescan
            sel |= 1u << (bg >> 6);
            lmax = -__builtin_inff(); larg = 0;
#pragma unroll
            for (int i = 0; i < 32; ++i) {
                float c = ((sel >> i) & 1u) ? -__builtin_inff() : v[i];
                if (c > lmax) { lmax = c; larg = i; }
            }
        }
    }

    // exact fp64 dot products for the 40 candidates
    const float* xr = x + (size_t)row * IND;
    float xv[12];
#pragma unroll
    for (int j = 0; j < 12; ++j) xv[j] = xr[j * 64 + lane];

    double exact = __builtin_inf();
    for (int c = 0; c < 40; ++c) {
        const int idx = __shfl(selidx, c);
        const float* wr = Wenc + (size_t)idx * IND;
        double s = 0.0;
#pragma unroll
        for (int j = 0; j < 12; ++j) s += (double)xv[j] * (double)wr[j * 64 + lane];
#pragma unroll
        for (int off = 32; off > 0; off >>= 1) s += __shfl_xor(s, off);
        if (lane == c) exact = s + (double)benc[idx];
    }

    // drop the 8 smallest exact values (tie: drop larger enc index first)
    bool picked = lane < 40;
    for (int it = 0; it < 8; ++it) {
        double bv = picked ? exact : __builtin_inf();
        int    bg = picked ? selidx : -1;
#pragma unroll
        for (int off = 32; off > 0; off >>= 1) {
            double ov = __shfl_xor(bv, off);
            int    og = __shfl_xor(bg, off);
            if (ov < bv || (ov == bv && og > bg)) { bv = ov; bg = og; }
        }
        if (picked && selidx == bg) picked = false;
        if (bg >= 0 && (bg & 63) == lane) sel &= ~(1u << (bg >> 6));
    }

    // h_sparse scatter (approx values — within tolerance; selection is exact)
    float* hs = hsp + (size_t)row * HID;
#pragma unroll
    for (int i = 0; i < 32; ++i)
        hs[i * 64 + lane] = ((sel >> i) & 1u) ? fmaxf(v[i], 0.0f) : 0.0f;

    // compact survivors for the decoder
    unsigned long long m = __ballot(picked);
    if (picked) {
        int rank = __popcll(m & ((1ull << lane) - 1ull));
        oidx[row * 32 + rank] = selidx;
        oval[row * 32 + rank] = fmaxf(selval, 0.0f);
    }
}

// ---------------- sparse decoder: rec = sum val_j * W_decT[idx_j] + b_dec ----
__global__ __launch_bounds__(256) void decode_rows(const int* __restrict__ oidx,
                                                   const float* __restrict__ oval,
                                                   const float* __restrict__ WdT,
                                                   const float* __restrict__ bdec,
                                                   float* __restrict__ rec)
{
    const int lane = threadIdx.x & 63;
    const int wave = threadIdx.x >> 6;
    const int row = blockIdx.x * 4 + wave;
    int   mi = 0; float mv = 0.0f;
    if (lane < 32) { mi = oidx[row * 32 + lane]; mv = oval[row * 32 + lane]; }

    float4v a0 = *(const float4v*)&bdec[lane * 4];
    float4v a1 = *(const float4v*)&bdec[256 + lane * 4];
    float4v a2 = *(const float4v*)&bdec[512 + lane * 4];

    for (int j = 0; j < 32; ++j) {
        const float val = __shfl(mv, j);
        const int   idx = __shfl(mi, j);
        if (val != 0.0f) {                     // wave-uniform branch
            const float* wr = WdT + (size_t)idx * IND;
            a0 += val * *(const float4v*)&wr[lane * 4];
            a1 += val * *(const float4v*)&wr[256 + lane * 4];
            a2 += val * *(const float4v*)&wr[512 + lane * 4];
        }
    }
    float* rp = rec + (size_t)row * IND;
    *(float4v*)&rp[lane * 4] = a0;
    *(float4v*)&rp[256 + lane * 4] = a1;
    *(float4v*)&rp[512 + lane * 4] = a2;
}

extern "C" void kernel_launch(void* const* d_in, const int* in_sizes, int n_in,
                              void* d_out, int out_size, void* d_ws, size_t ws_size,
                              hipStream_t stream)
{
    const float* x    = (const float*)d_in[0];
    const float* Wenc = (const float*)d_in[1];
    const float* benc = (const float*)d_in[2];
    const float* Wdec = (const float*)d_in[3];
    const float* bdec = (const float*)d_in[4];

    float* out  = (float*)d_out;
    float* rec  = out;                                           // 32768*768
    float* hsp  = out + (size_t)BATCH_N * IND;                   // 32768*2048
    float* hpre = out + (size_t)BATCH_N * IND + (size_t)BATCH_N * HID;

    char* ws = (char*)d_ws;
    _Float16* Whi = (_Float16*)ws;                 // 2048*768*2 = 3,145,728 B
    float*    WdT = (float*)(ws + 3145728);        // 6,291,456 B
    int*     tidx = (int*)(ws + 9437184);          // 4,194,304 B
    float*   tval = (float*)(ws + 13631488);       // 4,194,304 B (end ~17 MiB)

    hipLaunchKernelGGL(prep_wenc,   dim3(1536), dim3(256), 0, stream, Wenc, Whi);
    hipLaunchKernelGGL(prep_wdec,   dim3(6144), dim3(256), 0, stream, Wdec, WdT);
    hipLaunchKernelGGL(gemm_enc,    dim3(4096), dim3(256), 0, stream, x, Whi, benc, hpre);
    hipLaunchKernelGGL(topk_refine, dim3(8192), dim3(256), 0, stream, hpre, x, Wenc, benc, hsp, tidx, tval);
    hipLaunchKernelGGL(decode_rows, dim3(8192), dim3(256), 0, stream, tidx, tval, WdT, bdec, rec);
}